// Round 3
// baseline (61.716 us; speedup 1.0000x reference)
//
#include <hip/hip_runtime.h>

// BilinearSampler: image (B,H,W,C) f32, grid (B,H,W,2) f32 -> out (B,H,W,C) f32
// B=16, H=256, W=256, C=32.
// Mapping: 8 threads per output pixel, each thread owns 4 channels (float4).
// Each neighbor gather is a coalesced 128B segment across the 8-lane group.
//
// R2 = R1 with ext_vector types for the nontemporal builtins (HIP_vector_type
// structs are rejected by __builtin_nontemporal_*):
//  - XCD-affinity block swizzle: 32768 blocks, 8 XCDs -> each XCD gets a
//    contiguous 4096-block chunk = exactly 2 batches -> 4MiB sampled working
//    set per XCD, fits the per-XCD 4MiB L2.
//  - Non-temporal store for out / non-temporal load for grid (streamed once,
//    keep L2 for image gathers).

constexpr int Bn = 16, Hn = 256, Wn = 256, Cn = 32;

typedef float f32x2 __attribute__((ext_vector_type(2)));
typedef float f32x4 __attribute__((ext_vector_type(4)));

__global__ __launch_bounds__(256) void BilinearSampler_29300266893747_kernel(
    const float* __restrict__ image,
    const float* __restrict__ grid,
    float* __restrict__ out)
{
    // XCD-aware bijective swizzle: XCD(bid) = bid % 8 (round-robin dispatch).
    // wid = (bid%8)*chunk + bid/8 gives XCD k the contiguous work range
    // [k*chunk, (k+1)*chunk). gridDim.x = 32768 is divisible by 8.
    const unsigned bid   = blockIdx.x;
    const unsigned chunk = gridDim.x >> 3;
    const unsigned wid   = (bid & 7u) * chunk + (bid >> 3);

    const long long t = (long long)wid * blockDim.x + threadIdx.x;

    const int q = (int)(t & 7);          // channel quad index: channels q*4..q*4+3
    const long long p = t >> 3;          // pixel index in [0, B*H*W)
    const int b = (int)(p >> 16);        // H*W = 65536

    // grid coords (float2 per pixel; 8 lanes of the same pixel broadcast).
    // Streamed exactly once -> non-temporal.
    const f32x2 g = __builtin_nontemporal_load((const f32x2*)grid + p);

    // match reference rounding order: ((g + 1) * (W-1)) / 2
    const float x = (g.x + 1.0f) * 255.0f * 0.5f;
    const float y = (g.y + 1.0f) * 255.0f * 0.5f;

    const float xf = floorf(x);
    const float yf = floorf(y);
    const int x0 = (int)xf;
    const int y0 = (int)yf;
    const int x1 = x0 + 1;
    const int y1 = y0 + 1;

    const int x0c = min(max(x0, 0), Wn - 1);
    const int x1c = min(max(x1, 0), Wn - 1);
    const int y0c = min(max(y0, 0), Hn - 1);
    const int y1c = min(max(y1, 0), Hn - 1);

    const float x0f = (float)x0c, x1f = (float)x1c;
    const float y0f = (float)y0c, y1f = (float)y1c;

    const float wa = (x1f - x) * (y1f - y);
    const float wb = (x1f - x) * (y - y0f);
    const float wc = (x - x0f) * (y1f - y);
    const float wd = (x - x0f) * (y - y0f);

    const float* img_b = image + (long long)b * Hn * Wn * Cn;
    const int co = q * 4;

    const f32x4 Ia = *(const f32x4*)(img_b + ((long long)y0c * Wn + x0c) * Cn + co);
    const f32x4 Ib = *(const f32x4*)(img_b + ((long long)y1c * Wn + x0c) * Cn + co);
    const f32x4 Ic = *(const f32x4*)(img_b + ((long long)y0c * Wn + x1c) * Cn + co);
    const f32x4 Id = *(const f32x4*)(img_b + ((long long)y1c * Wn + x1c) * Cn + co);

    const f32x4 o = wa * Ia + wb * Ib + wc * Ic + wd * Id;

    // out is written once and never re-read -> non-temporal.
    __builtin_nontemporal_store(o, (f32x4*)(out + p * Cn + co));
}

extern "C" void kernel_launch(void* const* d_in, const int* in_sizes, int n_in,
                              void* d_out, int out_size, void* d_ws, size_t ws_size,
                              hipStream_t stream) {
    const float* image = (const float*)d_in[0];
    const float* grid  = (const float*)d_in[1];
    float* out = (float*)d_out;

    const long long total = (long long)Bn * Hn * Wn * 8;  // 8,388,608 threads
    const int block = 256;
    const int nblocks = (int)((total + block - 1) / block);  // 32768

    BilinearSampler_29300266893747_kernel<<<nblocks, block, 0, stream>>>(image, grid, out);
}

// Round 4
// 36.761 us; speedup vs baseline: 1.6789x; 1.6789x over previous
//
#include <hip/hip_runtime.h>

// BilinearSampler: image (B,H,W,C) f32, grid (B,H,W,2) f32 -> out (B,H,W,C) f32
// B=16, H=256, W=256, C=32.
//
// R3: ILP probe — 2 pixels per thread (8 independent 128B gathers in flight
// per wave). Discriminates latency-bound (helps) vs line-throughput-bound
// (flat). Keeps XCD-affinity swizzle + NT store; grid load back to temporal.
//
// Mapping: block = 256 threads = 32 pixel-slots x 8 channel-quads.
// Block covers 64 consecutive pixels: slot s handles p0 = base+s and
// p1 = base+32+s, so both store instructions per wave are 1KiB contiguous.

constexpr int Bn = 16, Hn = 256, Wn = 256, Cn = 32;

typedef float f32x2 __attribute__((ext_vector_type(2)));
typedef float f32x4 __attribute__((ext_vector_type(4)));

__global__ __launch_bounds__(256) void BilinearSampler_29300266893747_kernel(
    const float* __restrict__ image,
    const float* __restrict__ grid,
    float* __restrict__ out)
{
    // XCD-aware bijective swizzle (gridDim.x = 16384, divisible by 8).
    const unsigned bid   = blockIdx.x;
    const unsigned chunk = gridDim.x >> 3;
    const unsigned wid   = (bid & 7u) * chunk + (bid >> 3);

    const int tid = threadIdx.x;
    const int q   = tid & 7;        // channel quad: channels q*4..q*4+3
    const int s   = tid >> 3;       // pixel slot in [0,32)
    const int co  = q * 4;

    const long long base = (long long)wid * 64;   // 64 pixels per block
    const long long p0 = base + s;
    const long long p1 = base + 32 + s;
    const int b = (int)(p0 >> 16);  // block never straddles a batch (65536%64==0)
    const float* img_b = image + (long long)b * Hn * Wn * Cn;

    // ---- coords for both pixels ----
    const f32x2 g0 = *((const f32x2*)grid + p0);
    const f32x2 g1 = *((const f32x2*)grid + p1);

    const float x_0 = (g0.x + 1.0f) * 255.0f * 0.5f;
    const float y_0 = (g0.y + 1.0f) * 255.0f * 0.5f;
    const float x_1 = (g1.x + 1.0f) * 255.0f * 0.5f;
    const float y_1 = (g1.y + 1.0f) * 255.0f * 0.5f;

    const float xf0 = floorf(x_0), yf0 = floorf(y_0);
    const float xf1 = floorf(x_1), yf1 = floorf(y_1);

    const int x00 = (int)xf0, y00 = (int)yf0;
    const int x01 = (int)xf1, y01 = (int)yf1;

    const int x0c0 = min(max(x00,     0), Wn - 1);
    const int x1c0 = min(max(x00 + 1, 0), Wn - 1);
    const int y0c0 = min(max(y00,     0), Hn - 1);
    const int y1c0 = min(max(y00 + 1, 0), Hn - 1);

    const int x0c1 = min(max(x01,     0), Wn - 1);
    const int x1c1 = min(max(x01 + 1, 0), Wn - 1);
    const int y0c1 = min(max(y01,     0), Hn - 1);
    const int y1c1 = min(max(y01 + 1, 0), Hn - 1);

    // element offsets within batch: (y*256 + x)*32 + co
    const int oa0 = (y0c0 << 13) + (x0c0 << 5) + co;
    const int oc0 = (y0c0 << 13) + (x1c0 << 5) + co;
    const int ob0 = (y1c0 << 13) + (x0c0 << 5) + co;
    const int od0 = (y1c0 << 13) + (x1c0 << 5) + co;

    const int oa1 = (y0c1 << 13) + (x0c1 << 5) + co;
    const int oc1 = (y0c1 << 13) + (x1c1 << 5) + co;
    const int ob1 = (y1c1 << 13) + (x0c1 << 5) + co;
    const int od1 = (y1c1 << 13) + (x1c1 << 5) + co;

    // ---- issue all 8 gathers before any use ----
    const f32x4 Ia0 = *(const f32x4*)(img_b + oa0);
    const f32x4 Ib0 = *(const f32x4*)(img_b + ob0);
    const f32x4 Ic0 = *(const f32x4*)(img_b + oc0);
    const f32x4 Id0 = *(const f32x4*)(img_b + od0);
    const f32x4 Ia1 = *(const f32x4*)(img_b + oa1);
    const f32x4 Ib1 = *(const f32x4*)(img_b + ob1);
    const f32x4 Ic1 = *(const f32x4*)(img_b + oc1);
    const f32x4 Id1 = *(const f32x4*)(img_b + od1);

    // ---- weights ----
    const float x0f0 = (float)x0c0, x1f0 = (float)x1c0;
    const float y0f0 = (float)y0c0, y1f0 = (float)y1c0;
    const float x0f1 = (float)x0c1, x1f1 = (float)x1c1;
    const float y0f1 = (float)y0c1, y1f1 = (float)y1c1;

    const float wa0 = (x1f0 - x_0) * (y1f0 - y_0);
    const float wb0 = (x1f0 - x_0) * (y_0 - y0f0);
    const float wc0 = (x_0 - x0f0) * (y1f0 - y_0);
    const float wd0 = (x_0 - x0f0) * (y_0 - y0f0);

    const float wa1 = (x1f1 - x_1) * (y1f1 - y_1);
    const float wb1 = (x1f1 - x_1) * (y_1 - y0f1);
    const float wc1 = (x_1 - x0f1) * (y1f1 - y_1);
    const float wd1 = (x_1 - x0f1) * (y_1 - y0f1);

    const f32x4 o0 = wa0 * Ia0 + wb0 * Ib0 + wc0 * Ic0 + wd0 * Id0;
    const f32x4 o1 = wa1 * Ia1 + wb1 * Ib1 + wc1 * Ic1 + wd1 * Id1;

    __builtin_nontemporal_store(o0, (f32x4*)(out + p0 * Cn + co));
    __builtin_nontemporal_store(o1, (f32x4*)(out + p1 * Cn + co));
}

extern "C" void kernel_launch(void* const* d_in, const int* in_sizes, int n_in,
                              void* d_out, int out_size, void* d_ws, size_t ws_size,
                              hipStream_t stream) {
    const float* image = (const float*)d_in[0];
    const float* grid  = (const float*)d_in[1];
    float* out = (float*)d_out;

    const long long total = (long long)Bn * Hn * Wn * 8 / 2;  // 4,194,304 threads
    const int block = 256;
    const int nblocks = (int)((total + block - 1) / block);   // 16384

    BilinearSampler_29300266893747_kernel<<<nblocks, block, 0, stream>>>(image, grid, out);
}

// Round 5
// 36.753 us; speedup vs baseline: 1.6792x; 1.0002x over previous
//
#include <hip/hip_runtime.h>

// BilinearSampler: image (B,H,W,C) f32, grid (B,H,W,2) f32 -> out (B,H,W,C) f32
// B=16, H=256, W=256, C=32.
//
// R4: 4 pixels per thread (16 independent 128B gathers in flight per wave).
// R3 (2 px/thread) gave -40% -> latency x outstanding bound confirmed; keep
// pushing ILP. Block = 256 threads covers 128 consecutive pixels; stores are
// 4x contiguous-1KiB-per-wave NT stores. XCD-affinity swizzle kept.

constexpr int Bn = 16, Hn = 256, Wn = 256, Cn = 32;
constexpr int PX = 4;   // pixels per thread

typedef float f32x2 __attribute__((ext_vector_type(2)));
typedef float f32x4 __attribute__((ext_vector_type(4)));

__global__ __launch_bounds__(256) void BilinearSampler_29300266893747_kernel(
    const float* __restrict__ image,
    const float* __restrict__ grid,
    float* __restrict__ out)
{
    // XCD-aware bijective swizzle (gridDim.x = 8192, divisible by 8).
    const unsigned bid   = blockIdx.x;
    const unsigned chunk = gridDim.x >> 3;
    const unsigned wid   = (bid & 7u) * chunk + (bid >> 3);

    const int tid = threadIdx.x;
    const int q   = tid & 7;        // channel quad: channels q*4..q*4+3
    const int s   = tid >> 3;       // pixel slot in [0,32)
    const int co  = q * 4;

    const long long base = (long long)wid * (32 * PX);  // 128 pixels per block
    const int b = (int)(base >> 16);   // 65536 % 128 == 0: no batch straddle
    const float* img_b = image + (long long)b * Hn * Wn * Cn;

    long long p[PX];
#pragma unroll
    for (int i = 0; i < PX; ++i) p[i] = base + 32 * i + s;

    // ---- load all grid coords first ----
    f32x2 g[PX];
#pragma unroll
    for (int i = 0; i < PX; ++i) g[i] = *((const f32x2*)grid + p[i]);

    // ---- compute offsets + weights ----
    int oa[PX], ob[PX], oc[PX], od[PX];
    float wa[PX], wb[PX], wc[PX], wd[PX];
#pragma unroll
    for (int i = 0; i < PX; ++i) {
        const float x = (g[i].x + 1.0f) * 255.0f * 0.5f;
        const float y = (g[i].y + 1.0f) * 255.0f * 0.5f;
        const float xf = floorf(x), yf = floorf(y);
        const int x0 = (int)xf, y0 = (int)yf;

        const int x0c = min(max(x0,     0), Wn - 1);
        const int x1c = min(max(x0 + 1, 0), Wn - 1);
        const int y0c = min(max(y0,     0), Hn - 1);
        const int y1c = min(max(y0 + 1, 0), Hn - 1);

        // element offsets within batch: (y*256 + x)*32 + co
        oa[i] = (y0c << 13) + (x0c << 5) + co;
        oc[i] = (y0c << 13) + (x1c << 5) + co;
        ob[i] = (y1c << 13) + (x0c << 5) + co;
        od[i] = (y1c << 13) + (x1c << 5) + co;

        const float x0f = (float)x0c, x1f = (float)x1c;
        const float y0f = (float)y0c, y1f = (float)y1c;
        wa[i] = (x1f - x) * (y1f - y);
        wb[i] = (x1f - x) * (y - y0f);
        wc[i] = (x - x0f) * (y1f - y);
        wd[i] = (x - x0f) * (y - y0f);
    }

    // ---- issue all 16 gathers before any use ----
    f32x4 Ia[PX], Ib[PX], Ic[PX], Id[PX];
#pragma unroll
    for (int i = 0; i < PX; ++i) {
        Ia[i] = *(const f32x4*)(img_b + oa[i]);
        Ib[i] = *(const f32x4*)(img_b + ob[i]);
        Ic[i] = *(const f32x4*)(img_b + oc[i]);
        Id[i] = *(const f32x4*)(img_b + od[i]);
    }

    // ---- blend + store ----
#pragma unroll
    for (int i = 0; i < PX; ++i) {
        const f32x4 o = wa[i] * Ia[i] + wb[i] * Ib[i] + wc[i] * Ic[i] + wd[i] * Id[i];
        __builtin_nontemporal_store(o, (f32x4*)(out + p[i] * Cn + co));
    }
}

extern "C" void kernel_launch(void* const* d_in, const int* in_sizes, int n_in,
                              void* d_out, int out_size, void* d_ws, size_t ws_size,
                              hipStream_t stream) {
    const float* image = (const float*)d_in[0];
    const float* grid  = (const float*)d_in[1];
    float* out = (float*)d_out;

    const long long total = (long long)Bn * Hn * Wn * 8 / PX;  // 2,097,152 threads
    const int block = 256;
    const int nblocks = (int)((total + block - 1) / block);    // 8192

    BilinearSampler_29300266893747_kernel<<<nblocks, block, 0, stream>>>(image, grid, out);
}